// Round 16
// baseline (237.057 us; speedup 1.0000x reference)
//
#include <hip/hip_runtime.h>
#include <stdint.h>

typedef __attribute__((ext_vector_type(8))) short bf16x8;
typedef __attribute__((ext_vector_type(4))) float f32x4;
typedef __attribute__((ext_vector_type(4))) unsigned int u32x4;

#define NSP 65536

// workspace byte offsets
#define WS_XN     0ULL         // 33554432  bf16 xnf fragment-native (kvctx + final)
#define WS_WFRAG  33554432ULL  // 524288    Wkv fragment buffer
#define WS_WEFRAG 34078720ULL  // 131072    Weff fragment buffer
#define WS_PART   34209792ULL  // 2048      stats partials -> reduced sumexp[512]
#define WS_AB     34211840ULL  // 2048      per-channel a,b
#define WS_CTX    34215936ULL  // 131072    ctx[8][64][64]
#define WS_G      34347008ULL  // 524288    G[512][256]  (reuses old W2 region)
#define WS_G2     34871296ULL  // 2048      g2[512]
#define WS_BEFF   35657728ULL  // 1024      beff[256]

// d_out scratch (consumed by k_ctxred before k_final overwrites d_out):
//   ctxp (f32)  [32MB .. 36MB)    256 blocks * 4096 partials
//   sump (f32)  [36MB .. +64KB)   [h*64+d][chunk32]

__device__ __forceinline__ unsigned short f2bf(float f) {
  union { float f; uint32_t u; } v; v.f = f;
  uint32_t r = v.u + 0x7FFFu + ((v.u >> 16) & 1u);
  return (unsigned short)(r >> 16);
}
__device__ __forceinline__ float bf2f(unsigned short b) {
  union { uint32_t u; float f; } v; v.u = ((uint32_t)b) << 16;
  return v.f;
}

// ---------------- GroupNorm stats ----------------
__global__ void k_stats(const float* __restrict__ x, float* __restrict__ part) {
  __shared__ float ss[256], sq[256];
  const int t = threadIdx.x, b = blockIdx.x;
  const f32x4* p = (const f32x4*)(x + (size_t)b * 65536);
  float s = 0.f, qq = 0.f;
  for (int k = 0; k < 64; ++k) {
    f32x4 v = __builtin_nontemporal_load(p + t + 256 * k);
    s  += v[0] + v[1] + v[2] + v[3];
    qq += v[0] * v[0] + v[1] * v[1] + v[2] * v[2] + v[3] * v[3];
  }
  ss[t] = s; sq[t] = qq;
  __syncthreads();
  for (int st = 128; st > 0; st >>= 1) {
    if (t < st) { ss[t] += ss[t + st]; sq[t] += sq[t + st]; }
    __syncthreads();
  }
  if (t == 0) { part[2 * b] = ss[0]; part[2 * b + 1] = sq[0]; }
}

// ---------------- per-channel a,b ----------------
__global__ void k_coef(const float* __restrict__ part, const float* __restrict__ gn_w,
                       const float* __restrict__ gn_b, float* __restrict__ ab) {
  const int c = threadIdx.x;
  const int g = c >> 3;
  float s = 0.f, q = 0.f;
  for (int j = 0; j < 8; ++j) { s += part[(g * 8 + j) * 2]; q += part[(g * 8 + j) * 2 + 1]; }
  const float inv = 1.0f / 524288.0f;
  const float mean = s * inv;
  const float var = q * inv - mean * mean;
  const float rstd = rsqrtf(var + 1e-5f);
  const float a = gn_w[c] * rstd;
  ab[c] = a;
  ab[256 + c] = gn_b[c] - mean * a;
}

// ---------------- normalize + cast -> fragment-native xnf only ----------------
__global__ void k_xn(const float* __restrict__ x, const float* __restrict__ ab,
                     unsigned short* __restrict__ xnf) {
  __shared__ float tile[64][66];
  const int t = threadIdx.x;
  const int nb = blockIdx.x, cb = blockIdx.y;
  {
    const int cl = t >> 2, nc = t & 3;
    const int c = cb * 64 + cl;
    const float a = ab[c], b = ab[256 + c];
    const f32x4* src = (const f32x4*)(x + (size_t)c * NSP + nb * 64 + nc * 16);
#pragma unroll
    for (int j = 0; j < 4; ++j) {
      f32x4 v = __builtin_nontemporal_load(src + j);
      v = v * a + b;
      *(f32x4*)&tile[cl][nc * 16 + j * 4] = v;
    }
  }
  __syncthreads();
  {
    const int l = t & 63, w0 = t >> 6;
    u32x4* xnf4 = (u32x4*)xnf;
#pragma unroll
    for (int u2 = 0; u2 < 2; ++u2) {
      const int fp = w0 + u2 * 4;          // 0..7
      const int fl = fp >> 1, ksl = fp & 1;
      union { unsigned short s[8]; u32x4 v; } pk2;
#pragma unroll
      for (int e = 0; e < 8; ++e)
        pk2.s[e] = f2bf(tile[ksl * 32 + (l >> 4) * 8 + e][fl * 16 + (l & 15)]);
      xnf4[((size_t)(nb * 4 + fl) * 8 + cb * 2 + ksl) * 64 + l] = pk2.v;
    }
  }
}

// ---------------- pre-permute Wkv rows into MFMA B-fragment order ----------------
__global__ void k_wfrag(const float* __restrict__ qkv_w, unsigned short* __restrict__ wf) {
  const int blk = blockIdx.x;                 // blk = ks*64 + cf
  const int l = threadIdx.x;
  const int row = 512 + (blk & 63) * 16 + (l & 15);
  const int c0 = (blk >> 6) * 32 + (l >> 4) * 8;
  const float* src = qkv_w + (size_t)row * 256 + c0;
  union { unsigned short s[8]; u32x4 v; } u;
#pragma unroll
  for (int j = 0; j < 8; ++j) u.s[j] = f2bf(src[j]);
  *(u32x4*)(wf + ((size_t)blk * 64 + l) * 8) = u.v;
}

// ---------------- fused KV-GEMM + exp + in-register context (round-12, 63us) ----------------
// 1 head/block; per 256-row super-tile each wave does 2 row-groups:
// group w from the 64KB staged LDS tile, group 8+w direct from global (L2-shared
// by the 8 same-chunk head-blocks on one XCD). VGPR ~116, no spill.
__launch_bounds__(512, 1)
__global__ void k_kvctx(const unsigned short* __restrict__ xnf,
                        const unsigned short* __restrict__ wfrag,
                        const float* __restrict__ qkv_b,
                        float* __restrict__ sump, float* __restrict__ ctxp) {
  __shared__ __align__(16) char lds[133120];
  const int t = threadIdx.x;
  const int w = t >> 6, l = t & 63;
  const int q = l & 15;
  const int h = blockIdx.x >> 5;               // head 0..7
  const int chunk = blockIdx.x & 31;           // 2048-row chunk

  // stage this head's wfrag slice (64 KB) once: [ph][ks][jj][l]
  {
    const u32x4* wsrc = (const u32x4*)wfrag;
    u32x4* wdst = (u32x4*)lds;
#pragma unroll
    for (int r = 0; r < 8; ++r) {
      const int e = r * 512 + t;
      const int entry = e >> 6, l2 = e & 63;
      const int ph = entry >> 5, ks = (entry >> 2) & 7, jj = entry & 3;
      wdst[e] = wsrc[((size_t)(ks * 64 + ph * 32 + h * 4 + jj)) * 64 + l2];
    }
  }

  const f32x4 fz = {0.f, 0.f, 0.f, 0.f};
  f32x4 ctxa[4][4];
#pragma unroll
  for (int a = 0; a < 4; ++a)
#pragma unroll
    for (int b = 0; b < 4; ++b) ctxa[a][b] = fz;
  float srow[4] = {0.f, 0.f, 0.f, 0.f};
  float bk[4], bv[4];
#pragma unroll
  for (int jj = 0; jj < 4; ++jj) {
    bk[jj] = qkv_b[512 + h * 64 + jj * 16 + q];
    bv[jj] = qkv_b[1024 + h * 64 + jj * 16 + q];
  }

  const u32x4* xnf4 = (const u32x4*)xnf;
  u32x4* xa4 = (u32x4*)(lds + 65536);

  for (int st = 0; st < 8; ++st) {
    const size_t rg0 = (size_t)chunk * 128 + st * 16;  // first row-group of super-tile
    __syncthreads();               // previous tile's reads done
#pragma unroll
    for (int r = 0; r < 8; ++r)
      xa4[r * 512 + t] = xnf4[rg0 * 512 + r * 512 + t];
    __syncthreads();
    const u32x4* gB = xnf4 + (rg0 + 8 + w) * 512 + l;

    // K phase: both groups share the bwk LDS reads
    f32x4 ak[2][4] = {{fz, fz, fz, fz}, {fz, fz, fz, fz}};
#pragma unroll
    for (int ks = 0; ks < 8; ++ks) {
      const bf16x8 xaA = *(const bf16x8*)(lds + 65536 + ((w * 8 + ks) * 64 + l) * 16);
      const bf16x8 xaB = *(const bf16x8*)(gB + ks * 64);
#pragma unroll
      for (int jj = 0; jj < 4; ++jj) {
        const bf16x8 bwk = *(const bf16x8*)(lds + ((ks * 4 + jj) * 64 + l) * 16);
        ak[0][jj] = __builtin_amdgcn_mfma_f32_16x16x32_bf16(xaA, bwk, ak[0][jj], 0, 0, 0);
        ak[1][jj] = __builtin_amdgcn_mfma_f32_16x16x32_bf16(xaB, bwk, ak[1][jj], 0, 0, 0);
      }
    }
    bf16x8 pk[4];
#pragma unroll
    for (int jj = 0; jj < 4; ++jj) {
      float s = 0.f;
      bf16x8 p;
#pragma unroll
      for (int r = 0; r < 4; ++r) {
        const unsigned short u0 = f2bf(__expf(ak[0][jj][r] + bk[jj]));
        const unsigned short u1 = f2bf(__expf(ak[1][jj][r] + bk[jj]));
        p[r] = (short)u0; p[r + 4] = (short)u1;
        s += bf2f(u0) + bf2f(u1);
      }
      pk[jj] = p;
      srow[jj] += s;
    }

    // V phase
    f32x4 av[2][4] = {{fz, fz, fz, fz}, {fz, fz, fz, fz}};
#pragma unroll
    for (int ks = 0; ks < 8; ++ks) {
      const bf16x8 xaA = *(const bf16x8*)(lds + 65536 + ((w * 8 + ks) * 64 + l) * 16);
      const bf16x8 xaB = *(const bf16x8*)(gB + ks * 64);
#pragma unroll
      for (int jj = 0; jj < 4; ++jj) {
        const bf16x8 bwv = *(const bf16x8*)(lds + (((8 + ks) * 4 + jj) * 64 + l) * 16);
        av[0][jj] = __builtin_amdgcn_mfma_f32_16x16x32_bf16(xaA, bwv, av[0][jj], 0, 0, 0);
        av[1][jj] = __builtin_amdgcn_mfma_f32_16x16x32_bf16(xaB, bwv, av[1][jj], 0, 0, 0);
      }
    }
    bf16x8 pv[4];
#pragma unroll
    for (int jj = 0; jj < 4; ++jj) {
      bf16x8 p;
#pragma unroll
      for (int r = 0; r < 4; ++r) {
        p[r]     = (short)f2bf(av[0][jj][r] + bv[jj]);
        p[r + 4] = (short)f2bf(av[1][jj][r] + bv[jj]);
      }
      pv[jj] = p;
    }

    // context accumulate: full K=32 (both groups)
#pragma unroll
    for (int ja = 0; ja < 4; ++ja)
#pragma unroll
      for (int jb = 0; jb < 4; ++jb)
        ctxa[ja][jb] = __builtin_amdgcn_mfma_f32_16x16x32_bf16(pk[ja], pv[jb], ctxa[ja][jb], 0, 0, 0);
  }

  // ---- block-level reduction (8 waves, same head) ----
  __syncthreads();
  {
    float* dw = (float*)lds + w * 4096 + l * 4;
#pragma unroll
    for (int ja = 0; ja < 4; ++ja)
#pragma unroll
      for (int jb = 0; jb < 4; ++jb)
        *(f32x4*)(dw + (ja * 4 + jb) * 256) = ctxa[ja][jb];
  }
  {
    float* srl = (float*)(lds + 131072);
#pragma unroll
    for (int jj = 0; jj < 4; ++jj) {
      float s = srow[jj];
      s += __shfl_xor(s, 16, 64);
      s += __shfl_xor(s, 32, 64);
      if (l < 16) srl[w * 64 + jj * 16 + q] = s;
    }
  }
  __syncthreads();
  {
    const float* dump = (const float*)lds;
    const f32x4 fz2 = {0.f, 0.f, 0.f, 0.f};
#pragma unroll
    for (int j = 0; j < 2; ++j) {
      const int m4 = j * 512 + t;            // 0..1024 f32x4 outputs
      f32x4 s = fz2;
#pragma unroll
      for (int w8 = 0; w8 < 8; ++w8)
        s += *(const f32x4*)(dump + w8 * 4096 + m4 * 4);
      *(f32x4*)(ctxp + ((size_t)(h * 32 + chunk) * 1024 + m4) * 4) = s;
    }
    if (t < 64) {
      const float* srl = (const float*)(lds + 131072);
      float s = 0.f;
#pragma unroll
      for (int w8 = 0; w8 < 8; ++w8) s += srl[w8 * 64 + t];
      sump[(size_t)(h * 64 + t) * 32 + chunk] = s;
    }
  }
}

// ---------------- reduce partials over 32 chunks ----------------
__global__ void k_ctxred(const float* __restrict__ ctxp, const float* __restrict__ sump,
                         float* __restrict__ ctx, float* __restrict__ sexp) {
  const int t = threadIdx.x;
  if (blockIdx.x < 64) {
    const int m4 = blockIdx.x * 128 + t;     // 0..8192
    const int h = m4 >> 10, p4 = m4 & 1023;
    f32x4 s = {0.f, 0.f, 0.f, 0.f};
#pragma unroll 8
    for (int c = 0; c < 32; ++c)
      s += *(const f32x4*)(ctxp + (((size_t)h * 32 + c) * 1024 + p4) * 4);
    const int jajb = p4 >> 6, ll = p4 & 63;
    const int ja = jajb >> 2, jb = jajb & 3;
    const int gg = ll >> 4, qq = ll & 15;
    float* cw = ctx + ((size_t)h * 64 + ja * 16 + gg * 4) * 64 + jb * 16 + qq;
    cw[0] = s[0]; cw[64] = s[1]; cw[128] = s[2]; cw[192] = s[3];
  } else {
    const int r = (blockIdx.x - 64) * 128 + t;
    float s = 0.f;
#pragma unroll 8
    for (int c = 0; c < 32; ++c) s += sump[(size_t)r * 32 + c];
    sexp[r] = s;
  }
}

// ---------------- G[(h,e)][c] = sum_d (ctx[h,d,e]/sexp[h,d]) * Wq[(h,d)][c] ----------------
// + g2[(h,e)] = sum_d ctxn * bq[(h,d)]     (one block per head)
__global__ void k_G(const float* __restrict__ ctx, const float* __restrict__ sexp,
                    const float* __restrict__ qkv_w, const float* __restrict__ qkv_b,
                    float* __restrict__ G, float* __restrict__ g2) {
  __shared__ float cn[64][65];
  __shared__ float sinv[64];
  const int h = blockIdx.x, t = threadIdx.x;
  if (t < 64) sinv[t] = 1.0f / sexp[h * 64 + t];
  __syncthreads();
#pragma unroll
  for (int j = 0; j < 16; ++j) {
    const int idx = j * 256 + t;             // 4096
    const int d = idx >> 6, e = idx & 63;
    cn[d][e] = ctx[(size_t)h * 4096 + idx] * sinv[d];
  }
  __syncthreads();
  const int c = t;
  for (int e8 = 0; e8 < 8; ++e8) {
    float acc[8] = {0.f, 0.f, 0.f, 0.f, 0.f, 0.f, 0.f, 0.f};
    for (int d = 0; d < 64; ++d) {
      const float wq = qkv_w[(size_t)(h * 64 + d) * 256 + c];
#pragma unroll
      for (int e = 0; e < 8; ++e) acc[e] += cn[d][e8 * 8 + e] * wq;
    }
#pragma unroll
    for (int e = 0; e < 8; ++e)
      G[(size_t)(h * 64 + e8 * 8 + e) * 256 + c] = acc[e];
  }
  if (t < 64) {
    float s = 0.f;
    for (int d = 0; d < 64; ++d) s += cn[d][t] * qkv_b[h * 64 + d];
    g2[h * 64 + t] = s;
  }
}

// ---------------- Weff = out_w @ G (+ beff) -> fragment order, fused ----------------
__global__ void k_weffrag(const float* __restrict__ out_w, const float* __restrict__ G,
                          const float* __restrict__ g2, const float* __restrict__ out_b,
                          unsigned short* __restrict__ wef, float* __restrict__ beff) {
  __shared__ float ow[16][513];
  __shared__ float wl[16][257];
  const int ro = blockIdx.x;      // 16 blocks, o-rows ro*16..+16
  const int t = threadIdx.x;      // 256
#pragma unroll
  for (int j = 0; j < 32; ++j) {
    const int idx = j * 256 + t;  // 8192
    ow[idx >> 9][idx & 511] = out_w[(size_t)(ro * 16 + (idx >> 9)) * 512 + (idx & 511)];
  }
  __syncthreads();
  const int c = t;
  float acc[16];
#pragma unroll
  for (int i = 0; i < 16; ++i) acc[i] = 0.f;
  for (int he = 0; he < 512; ++he) {
    const float gv = G[(size_t)he * 256 + c];
#pragma unroll
    for (int o16 = 0; o16 < 16; ++o16) acc[o16] += ow[o16][he] * gv;
  }
#pragma unroll
  for (int o16 = 0; o16 < 16; ++o16) wl[o16][c] = acc[o16];
  if (t < 16) {
    float b = out_b[ro * 16 + t];
    for (int he = 0; he < 512; ++he) b += ow[t][he] * g2[he];
    beff[ro * 16 + t] = b;
  }
  __syncthreads();
#pragma unroll
  for (int it = 0; it < 2; ++it) {
    const int idx = it * 256 + t;  // ks*64 + l
    const int ks = idx >> 6, l = idx & 63;
    const int rloc = l & 15, c0 = ks * 32 + (l >> 4) * 8;
    union { unsigned short s[8]; u32x4 v; } u;
#pragma unroll
    for (int j2 = 0; j2 < 8; ++j2) u.s[j2] = f2bf(wl[rloc][c0 + j2]);
    *(u32x4*)(wef + ((size_t)(ks * 16 + ro) * 64 + l) * 8) = u.v;
  }
}

// ---------------- final GEMM (reads xnf fragments) + coalesced epilogue ----------------
__launch_bounds__(256, 2)
__global__ void k_final(const unsigned short* __restrict__ xnf,
                        const unsigned short* __restrict__ wef,
                        const float* __restrict__ beff,
                        float* __restrict__ out) {
  __shared__ unsigned short xlds[32768];   // 64 KB fragment staging, reused for transpose
  const int t = threadIdx.x;
  const int w = t >> 6, l = t & 63;
  const int q = l & 15, g = l >> 4;
  const int si = w >> 1, sj = w & 1;
  // XCD swizzle: each XCD (bid%8) owns a contiguous 8192-column span of every row
  const int bid = (blockIdx.x & 7) * 64 + (blockIdx.x >> 3);
  const size_t n0 = (size_t)bid * 128;
  {
    const u32x4* gs = (const u32x4*)xnf + (size_t)bid * 4096;
    u32x4* ld = (u32x4*)xlds;
#pragma unroll
    for (int k2 = 0; k2 < 16; ++k2)
      ld[t + 256 * k2] = gs[t + 256 * k2];
  }
  __syncthreads();
  const f32x4 fz = {0.f, 0.f, 0.f, 0.f};
  f32x4 acc[4][8];
#pragma unroll
  for (int i = 0; i < 4; ++i)
#pragma unroll
    for (int j = 0; j < 8; ++j) acc[i][j] = fz;
#pragma unroll
  for (int ks = 0; ks < 8; ++ks) {
    bf16x8 xa[4];
#pragma unroll
    for (int i = 0; i < 4; ++i)
      xa[i] = *(const bf16x8*)((const char*)xlds + (((si * 4 + i) * 8 + ks) * 64 + l) * 16);
#pragma unroll
    for (int jj = 0; jj < 8; ++jj) {
      const bf16x8 bw = *(const bf16x8*)(wef + (((size_t)(ks * 16 + sj * 8 + jj)) * 64 + l) * 8);
#pragma unroll
      for (int i = 0; i < 4; ++i)
        acc[i][jj] = __builtin_amdgcn_mfma_f32_16x16x32_bf16(xa[i], bw, acc[i][jj], 0, 0, 0);
    }
  }
  // transpose epilogue through LDS: 4 rounds of 64 output rows
  __syncthreads();
  float* trf = (float*)xlds;               // [64][129] floats
#pragma unroll
  for (int k4 = 0; k4 < 4; ++k4) {
    if ((k4 >> 1) == sj) {
#pragma unroll
      for (int jj2 = 0; jj2 < 4; ++jj2) {
        const int jj = (k4 & 1) * 4 + jj2;
        const float be = beff[sj * 128 + jj * 16 + q];
#pragma unroll
        for (int i = 0; i < 4; ++i)
#pragma unroll
          for (int r = 0; r < 4; ++r)
            trf[(jj2 * 16 + q) * 129 + si * 64 + i * 16 + g * 4 + r] = acc[i][jj][r] + be;
      }
    }
    __syncthreads();
#pragma unroll
    for (int j = 0; j < 32; ++j) {
      const int mm = j * 256 + t;          // 8192 floats
      const int ol = mm >> 7, cc = mm & 127;
      out[(size_t)(k4 * 64 + ol) * NSP + n0 + cc] = trf[ol * 129 + cc];
    }
    __syncthreads();
  }
}

extern "C" void kernel_launch(void* const* d_in, const int* in_sizes, int n_in,
                              void* d_out, int out_size, void* d_ws, size_t ws_size,
                              hipStream_t stream) {
  const float* x     = (const float*)d_in[0];
  const float* gn_w  = (const float*)d_in[1];
  const float* gn_b  = (const float*)d_in[2];
  const float* qkv_w = (const float*)d_in[3];
  const float* qkv_b = (const float*)d_in[4];
  const float* out_w = (const float*)d_in[5];
  const float* out_b = (const float*)d_in[6];
  char* ws = (char*)d_ws;
  unsigned short* xnf = (unsigned short*)(ws + WS_XN);
  unsigned short* wf  = (unsigned short*)(ws + WS_WFRAG);
  unsigned short* wef = (unsigned short*)(ws + WS_WEFRAG);
  float* part   = (float*)(ws + WS_PART);   // stats partials, then sexp[512]
  float* ab     = (float*)(ws + WS_AB);
  float* ctx    = (float*)(ws + WS_CTX);
  float* G      = (float*)(ws + WS_G);
  float* g2     = (float*)(ws + WS_G2);
  float* beff   = (float*)(ws + WS_BEFF);
  float* out    = (float*)d_out;
  // d_out scratch (consumed by k_ctxred before k_final writes out):
  float* ctxp = (float*)((char*)d_out + 33554432ULL);       //  4 MB
  float* sump = (float*)((char*)d_out + 37748736ULL);       // 64 KB

  k_wfrag<<<512, 64, 0, stream>>>(qkv_w, wf);
  k_stats<<<256, 256, 0, stream>>>(x, part);
  k_coef<<<1, 256, 0, stream>>>(part, gn_w, gn_b, ab);
  k_xn<<<dim3(1024, 4), 256, 0, stream>>>(x, ab, xnf);
  k_kvctx<<<256, 512, 0, stream>>>(xnf, wf, qkv_b, sump, ctxp);
  k_ctxred<<<68, 128, 0, stream>>>(ctxp, sump, ctx, part);
  k_G<<<8, 256, 0, stream>>>(ctx, part, qkv_w, qkv_b, G, g2);
  k_weffrag<<<16, 256, 0, stream>>>(out_w, G, g2, out_b, wef, beff);
  k_final<<<512, 256, 0, stream>>>(xnf, wef, beff, out);
}

// Round 17
// 172.144 us; speedup vs baseline: 1.3771x; 1.3771x over previous
//
#include <hip/hip_runtime.h>
#include <stdint.h>

typedef __attribute__((ext_vector_type(8))) short bf16x8;
typedef __attribute__((ext_vector_type(4))) float f32x4;
typedef __attribute__((ext_vector_type(4))) unsigned int u32x4;

#define NSP 65536

// workspace byte offsets
#define WS_XN     0ULL         // 33554432  bf16 xnf fragment-native (kvctx + final)
#define WS_WFRAG  33554432ULL  // 524288    Wkv fragment buffer
#define WS_WEFRAG 34078720ULL  // 131072    Weff fragment buffer
#define WS_PART   34209792ULL  // 2048      stats partials -> reduced sumexp[512]
#define WS_AB     34211840ULL  // 2048      per-channel a,b
#define WS_CTX    34215936ULL  // 131072    ctx[8][64][64]
#define WS_W2     34347008ULL  // 1048576   W2[256][512]
#define WS_WEFF   35395584ULL  // 262144    Weff[256][256]
#define WS_BEFF   35657728ULL  // 1024      beff[256]

// d_out scratch (consumed by k_ctxred before k_final overwrites d_out):
//   ctxp (f32)  [32MB .. 36MB)    256 blocks * 4096 partials
//   sump (f32)  [36MB .. +64KB)   [h*64+d][chunk32]

__device__ __forceinline__ unsigned short f2bf(float f) {
  union { float f; uint32_t u; } v; v.f = f;
  uint32_t r = v.u + 0x7FFFu + ((v.u >> 16) & 1u);
  return (unsigned short)(r >> 16);
}
__device__ __forceinline__ float bf2f(unsigned short b) {
  union { uint32_t u; float f; } v; v.u = ((uint32_t)b) << 16;
  return v.f;
}

// ---------------- GroupNorm stats ----------------
__global__ void k_stats(const float* __restrict__ x, float* __restrict__ part) {
  __shared__ float ss[256], sq[256];
  const int t = threadIdx.x, b = blockIdx.x;
  const f32x4* p = (const f32x4*)(x + (size_t)b * 65536);
  float s = 0.f, qq = 0.f;
  for (int k = 0; k < 64; ++k) {
    f32x4 v = __builtin_nontemporal_load(p + t + 256 * k);
    s  += v[0] + v[1] + v[2] + v[3];
    qq += v[0] * v[0] + v[1] * v[1] + v[2] * v[2] + v[3] * v[3];
  }
  ss[t] = s; sq[t] = qq;
  __syncthreads();
  for (int st = 128; st > 0; st >>= 1) {
    if (t < st) { ss[t] += ss[t + st]; sq[t] += sq[t + st]; }
    __syncthreads();
  }
  if (t == 0) { part[2 * b] = ss[0]; part[2 * b + 1] = sq[0]; }
}

// ---------------- per-channel a,b ----------------
__global__ void k_coef(const float* __restrict__ part, const float* __restrict__ gn_w,
                       const float* __restrict__ gn_b, float* __restrict__ ab) {
  const int c = threadIdx.x;
  const int g = c >> 3;
  float s = 0.f, q = 0.f;
  for (int j = 0; j < 8; ++j) { s += part[(g * 8 + j) * 2]; q += part[(g * 8 + j) * 2 + 1]; }
  const float inv = 1.0f / 524288.0f;
  const float mean = s * inv;
  const float var = q * inv - mean * mean;
  const float rstd = rsqrtf(var + 1e-5f);
  const float a = gn_w[c] * rstd;
  ab[c] = a;
  ab[256 + c] = gn_b[c] - mean * a;
}

// ---------------- normalize + cast -> fragment-native xnf only ----------------
__global__ void k_xn(const float* __restrict__ x, const float* __restrict__ ab,
                     unsigned short* __restrict__ xnf) {
  __shared__ float tile[64][66];
  const int t = threadIdx.x;
  const int nb = blockIdx.x, cb = blockIdx.y;
  {
    const int cl = t >> 2, nc = t & 3;
    const int c = cb * 64 + cl;
    const float a = ab[c], b = ab[256 + c];
    const f32x4* src = (const f32x4*)(x + (size_t)c * NSP + nb * 64 + nc * 16);
#pragma unroll
    for (int j = 0; j < 4; ++j) {
      f32x4 v = __builtin_nontemporal_load(src + j);
      v = v * a + b;
      *(f32x4*)&tile[cl][nc * 16 + j * 4] = v;
    }
  }
  __syncthreads();
  {
    const int l = t & 63, w0 = t >> 6;
    u32x4* xnf4 = (u32x4*)xnf;
#pragma unroll
    for (int u2 = 0; u2 < 2; ++u2) {
      const int fp = w0 + u2 * 4;          // 0..7
      const int fl = fp >> 1, ksl = fp & 1;
      union { unsigned short s[8]; u32x4 v; } pk2;
#pragma unroll
      for (int e = 0; e < 8; ++e)
        pk2.s[e] = f2bf(tile[ksl * 32 + (l >> 4) * 8 + e][fl * 16 + (l & 15)]);
      xnf4[((size_t)(nb * 4 + fl) * 8 + cb * 2 + ksl) * 64 + l] = pk2.v;
    }
  }
}

// ---------------- pre-permute Wkv rows into MFMA B-fragment order ----------------
__global__ void k_wfrag(const float* __restrict__ qkv_w, unsigned short* __restrict__ wf) {
  const int blk = blockIdx.x;                 // blk = ks*64 + cf
  const int l = threadIdx.x;
  const int row = 512 + (blk & 63) * 16 + (l & 15);
  const int c0 = (blk >> 6) * 32 + (l >> 4) * 8;
  const float* src = qkv_w + (size_t)row * 256 + c0;
  union { unsigned short s[8]; u32x4 v; } u;
#pragma unroll
  for (int j = 0; j < 8; ++j) u.s[j] = f2bf(src[j]);
  *(u32x4*)(wf + ((size_t)blk * 64 + l) * 8) = u.v;
}

// ---------------- fused KV-GEMM + exp + in-register context (round-12, 63us) ----------------
__launch_bounds__(512, 1)
__global__ void k_kvctx(const unsigned short* __restrict__ xnf,
                        const unsigned short* __restrict__ wfrag,
                        const float* __restrict__ qkv_b,
                        float* __restrict__ sump, float* __restrict__ ctxp) {
  __shared__ __align__(16) char lds[133120];
  const int t = threadIdx.x;
  const int w = t >> 6, l = t & 63;
  const int q = l & 15;
  const int h = blockIdx.x >> 5;               // head 0..7
  const int chunk = blockIdx.x & 31;           // 2048-row chunk

  // stage this head's wfrag slice (64 KB) once: [ph][ks][jj][l]
  {
    const u32x4* wsrc = (const u32x4*)wfrag;
    u32x4* wdst = (u32x4*)lds;
#pragma unroll
    for (int r = 0; r < 8; ++r) {
      const int e = r * 512 + t;
      const int entry = e >> 6, l2 = e & 63;
      const int ph = entry >> 5, ks = (entry >> 2) & 7, jj = entry & 3;
      wdst[e] = wsrc[((size_t)(ks * 64 + ph * 32 + h * 4 + jj)) * 64 + l2];
    }
  }

  const f32x4 fz = {0.f, 0.f, 0.f, 0.f};
  f32x4 ctxa[4][4];
#pragma unroll
  for (int a = 0; a < 4; ++a)
#pragma unroll
    for (int b = 0; b < 4; ++b) ctxa[a][b] = fz;
  float srow[4] = {0.f, 0.f, 0.f, 0.f};
  float bk[4], bv[4];
#pragma unroll
  for (int jj = 0; jj < 4; ++jj) {
    bk[jj] = qkv_b[512 + h * 64 + jj * 16 + q];
    bv[jj] = qkv_b[1024 + h * 64 + jj * 16 + q];
  }

  const u32x4* xnf4 = (const u32x4*)xnf;
  u32x4* xa4 = (u32x4*)(lds + 65536);

  for (int st = 0; st < 8; ++st) {
    const size_t rg0 = (size_t)chunk * 128 + st * 16;  // first row-group of super-tile
    __syncthreads();               // previous tile's reads done
#pragma unroll
    for (int r = 0; r < 8; ++r)
      xa4[r * 512 + t] = xnf4[rg0 * 512 + r * 512 + t];
    __syncthreads();
    const u32x4* gB = xnf4 + (rg0 + 8 + w) * 512 + l;

    // K phase: both groups share the bwk LDS reads
    f32x4 ak[2][4] = {{fz, fz, fz, fz}, {fz, fz, fz, fz}};
#pragma unroll
    for (int ks = 0; ks < 8; ++ks) {
      const bf16x8 xaA = *(const bf16x8*)(lds + 65536 + ((w * 8 + ks) * 64 + l) * 16);
      const bf16x8 xaB = *(const bf16x8*)(gB + ks * 64);
#pragma unroll
      for (int jj = 0; jj < 4; ++jj) {
        const bf16x8 bwk = *(const bf16x8*)(lds + ((ks * 4 + jj) * 64 + l) * 16);
        ak[0][jj] = __builtin_amdgcn_mfma_f32_16x16x32_bf16(xaA, bwk, ak[0][jj], 0, 0, 0);
        ak[1][jj] = __builtin_amdgcn_mfma_f32_16x16x32_bf16(xaB, bwk, ak[1][jj], 0, 0, 0);
      }
    }
    bf16x8 pk[4];
#pragma unroll
    for (int jj = 0; jj < 4; ++jj) {
      float s = 0.f;
      bf16x8 p;
#pragma unroll
      for (int r = 0; r < 4; ++r) {
        const unsigned short u0 = f2bf(__expf(ak[0][jj][r] + bk[jj]));
        const unsigned short u1 = f2bf(__expf(ak[1][jj][r] + bk[jj]));
        p[r] = (short)u0; p[r + 4] = (short)u1;
        s += bf2f(u0) + bf2f(u1);
      }
      pk[jj] = p;
      srow[jj] += s;
    }

    // V phase
    f32x4 av[2][4] = {{fz, fz, fz, fz}, {fz, fz, fz, fz}};
#pragma unroll
    for (int ks = 0; ks < 8; ++ks) {
      const bf16x8 xaA = *(const bf16x8*)(lds + 65536 + ((w * 8 + ks) * 64 + l) * 16);
      const bf16x8 xaB = *(const bf16x8*)(gB + ks * 64);
#pragma unroll
      for (int jj = 0; jj < 4; ++jj) {
        const bf16x8 bwv = *(const bf16x8*)(lds + (((8 + ks) * 4 + jj) * 64 + l) * 16);
        av[0][jj] = __builtin_amdgcn_mfma_f32_16x16x32_bf16(xaA, bwv, av[0][jj], 0, 0, 0);
        av[1][jj] = __builtin_amdgcn_mfma_f32_16x16x32_bf16(xaB, bwv, av[1][jj], 0, 0, 0);
      }
    }
    bf16x8 pv[4];
#pragma unroll
    for (int jj = 0; jj < 4; ++jj) {
      bf16x8 p;
#pragma unroll
      for (int r = 0; r < 4; ++r) {
        p[r]     = (short)f2bf(av[0][jj][r] + bv[jj]);
        p[r + 4] = (short)f2bf(av[1][jj][r] + bv[jj]);
      }
      pv[jj] = p;
    }

    // context accumulate: full K=32 (both groups)
#pragma unroll
    for (int ja = 0; ja < 4; ++ja)
#pragma unroll
      for (int jb = 0; jb < 4; ++jb)
        ctxa[ja][jb] = __builtin_amdgcn_mfma_f32_16x16x32_bf16(pk[ja], pv[jb], ctxa[ja][jb], 0, 0, 0);
  }

  // ---- block-level reduction (8 waves, same head) ----
  __syncthreads();
  {
    float* dw = (float*)lds + w * 4096 + l * 4;
#pragma unroll
    for (int ja = 0; ja < 4; ++ja)
#pragma unroll
      for (int jb = 0; jb < 4; ++jb)
        *(f32x4*)(dw + (ja * 4 + jb) * 256) = ctxa[ja][jb];
  }
  {
    float* srl = (float*)(lds + 131072);
#pragma unroll
    for (int jj = 0; jj < 4; ++jj) {
      float s = srow[jj];
      s += __shfl_xor(s, 16, 64);
      s += __shfl_xor(s, 32, 64);
      if (l < 16) srl[w * 64 + jj * 16 + q] = s;
    }
  }
  __syncthreads();
  {
    const float* dump = (const float*)lds;
    const f32x4 fz2 = {0.f, 0.f, 0.f, 0.f};
#pragma unroll
    for (int j = 0; j < 2; ++j) {
      const int m4 = j * 512 + t;            // 0..1024 f32x4 outputs
      f32x4 s = fz2;
#pragma unroll
      for (int w8 = 0; w8 < 8; ++w8)
        s += *(const f32x4*)(dump + w8 * 4096 + m4 * 4);
      *(f32x4*)(ctxp + ((size_t)(h * 32 + chunk) * 1024 + m4) * 4) = s;
    }
    if (t < 64) {
      const float* srl = (const float*)(lds + 131072);
      float s = 0.f;
#pragma unroll
      for (int w8 = 0; w8 < 8; ++w8) s += srl[w8 * 64 + t];
      sump[(size_t)(h * 64 + t) * 32 + chunk] = s;
    }
  }
}

// ---------------- reduce partials over 32 chunks ----------------
__global__ void k_ctxred(const float* __restrict__ ctxp, const float* __restrict__ sump,
                         float* __restrict__ ctx, float* __restrict__ sexp) {
  const int t = threadIdx.x;
  if (blockIdx.x < 64) {
    const int m4 = blockIdx.x * 128 + t;     // 0..8192
    const int h = m4 >> 10, p4 = m4 & 1023;
    f32x4 s = {0.f, 0.f, 0.f, 0.f};
#pragma unroll 8
    for (int c = 0; c < 32; ++c)
      s += *(const f32x4*)(ctxp + (((size_t)h * 32 + c) * 1024 + p4) * 4);
    const int jajb = p4 >> 6, ll = p4 & 63;
    const int ja = jajb >> 2, jb = jajb & 3;
    const int gg = ll >> 4, qq = ll & 15;
    float* cw = ctx + ((size_t)h * 64 + ja * 16 + gg * 4) * 64 + jb * 16 + qq;
    cw[0] = s[0]; cw[64] = s[1]; cw[128] = s[2]; cw[192] = s[3];
  } else {
    const int r = (blockIdx.x - 64) * 128 + t;
    float s = 0.f;
#pragma unroll 8
    for (int c = 0; c < 32; ++c) s += sump[(size_t)r * 32 + c];
    sexp[r] = s;
  }
}

// ---------------- W2 ----------------
__global__ void k_w2(const float* __restrict__ out_w, const float* __restrict__ ctx,
                     const float* __restrict__ sexp, float* __restrict__ w2) {
  const int r = blockIdx.x;
  const int h = r >> 6, d = r & 63;
  __shared__ float row[64];
  __shared__ float sinv;
  const int t = threadIdx.x;
  if (t < 64) row[t] = ctx[((size_t)h * 64 + d) * 64 + t];
  if (t == 0) sinv = 1.0f / sexp[r];
  __syncthreads();
  float a = 0.f;
  const float* wp = out_w + (size_t)t * 512 + h * 64;
#pragma unroll 8
  for (int e = 0; e < 64; ++e) a += wp[e] * row[e];
  w2[(size_t)t * 512 + r] = a * sinv;
}

// ---------------- Weff = W2 @ Wq  (+ beff folded in) ----------------
__global__ void k_weff(const float* __restrict__ w2, const float* __restrict__ qkv_w,
                       const float* __restrict__ qkv_b, const float* __restrict__ out_b,
                       float* __restrict__ weff, float* __restrict__ beff) {
  const int o = blockIdx.x;
  const int c = threadIdx.x;
  __shared__ float row[512];
  __shared__ float red[256];
  row[c] = w2[(size_t)o * 512 + c];
  row[256 + c] = w2[(size_t)o * 512 + 256 + c];
  __syncthreads();
  float a = 0.f;
#pragma unroll 8
  for (int r = 0; r < 512; ++r) a += row[r] * qkv_w[(size_t)r * 256 + c];
  weff[o * 256 + c] = a;
  red[c] = row[c] * qkv_b[c] + row[256 + c] * qkv_b[256 + c];
  __syncthreads();
  for (int st = 128; st > 0; st >>= 1) {
    if (c < st) red[c] += red[c + st];
    __syncthreads();
  }
  if (c == 0) beff[o] = out_b[o] + red[0];
}

// ---------------- Weff -> fragment order ----------------
__global__ void k_wefrag(const float* __restrict__ weff, unsigned short* __restrict__ wf) {
  const int blk = blockIdx.x;
  const int l = threadIdx.x;
  const int row = (blk & 15) * 16 + (l & 15);
  const int c0 = (blk >> 4) * 32 + (l >> 4) * 8;
  const float* src = weff + (size_t)row * 256 + c0;
  union { unsigned short s[8]; u32x4 v; } u;
#pragma unroll
  for (int j = 0; j < 8; ++j) u.s[j] = f2bf(src[j]);
  *(u32x4*)(wf + ((size_t)blk * 64 + l) * 8) = u.v;
}

// ---------------- final GEMM (reads xnf fragments) + coalesced epilogue ----------------
__launch_bounds__(256, 2)
__global__ void k_final(const unsigned short* __restrict__ xnf,
                        const unsigned short* __restrict__ wef,
                        const float* __restrict__ beff,
                        float* __restrict__ out) {
  __shared__ unsigned short xlds[32768];   // 64 KB fragment staging, reused for transpose
  const int t = threadIdx.x;
  const int w = t >> 6, l = t & 63;
  const int q = l & 15, g = l >> 4;
  const int si = w >> 1, sj = w & 1;
  // XCD swizzle: each XCD (bid%8) owns a contiguous 8192-column span of every row
  const int bid = (blockIdx.x & 7) * 64 + (blockIdx.x >> 3);
  const size_t n0 = (size_t)bid * 128;
  {
    const u32x4* gs = (const u32x4*)xnf + (size_t)bid * 4096;
    u32x4* ld = (u32x4*)xlds;
#pragma unroll
    for (int k2 = 0; k2 < 16; ++k2)
      ld[t + 256 * k2] = gs[t + 256 * k2];
  }
  __syncthreads();
  const f32x4 fz = {0.f, 0.f, 0.f, 0.f};
  f32x4 acc[4][8];
#pragma unroll
  for (int i = 0; i < 4; ++i)
#pragma unroll
    for (int j = 0; j < 8; ++j) acc[i][j] = fz;
#pragma unroll
  for (int ks = 0; ks < 8; ++ks) {
    bf16x8 xa[4];
#pragma unroll
    for (int i = 0; i < 4; ++i)
      xa[i] = *(const bf16x8*)((const char*)xlds + (((si * 4 + i) * 8 + ks) * 64 + l) * 16);
#pragma unroll
    for (int jj = 0; jj < 8; ++jj) {
      const bf16x8 bw = *(const bf16x8*)(wef + (((size_t)(ks * 16 + sj * 8 + jj)) * 64 + l) * 8);
#pragma unroll
      for (int i = 0; i < 4; ++i)
        acc[i][jj] = __builtin_amdgcn_mfma_f32_16x16x32_bf16(xa[i], bw, acc[i][jj], 0, 0, 0);
    }
  }
  // transpose epilogue through LDS: 4 rounds of 64 output rows
  __syncthreads();
  float* trf = (float*)xlds;               // [64][129] floats
#pragma unroll
  for (int k4 = 0; k4 < 4; ++k4) {
    if ((k4 >> 1) == sj) {
#pragma unroll
      for (int jj2 = 0; jj2 < 4; ++jj2) {
        const int jj = (k4 & 1) * 4 + jj2;
        const float be = beff[sj * 128 + jj * 16 + q];
#pragma unroll
        for (int i = 0; i < 4; ++i)
#pragma unroll
          for (int r = 0; r < 4; ++r)
            trf[(jj2 * 16 + q) * 129 + si * 64 + i * 16 + g * 4 + r] = acc[i][jj][r] + be;
      }
    }
    __syncthreads();
#pragma unroll
    for (int j = 0; j < 32; ++j) {
      const int mm = j * 256 + t;          // 8192 floats
      const int ol = mm >> 7, cc = mm & 127;
      out[(size_t)(k4 * 64 + ol) * NSP + n0 + cc] = trf[ol * 129 + cc];
    }
    __syncthreads();
  }
}

extern "C" void kernel_launch(void* const* d_in, const int* in_sizes, int n_in,
                              void* d_out, int out_size, void* d_ws, size_t ws_size,
                              hipStream_t stream) {
  const float* x     = (const float*)d_in[0];
  const float* gn_w  = (const float*)d_in[1];
  const float* gn_b  = (const float*)d_in[2];
  const float* qkv_w = (const float*)d_in[3];
  const float* qkv_b = (const float*)d_in[4];
  const float* out_w = (const float*)d_in[5];
  const float* out_b = (const float*)d_in[6];
  char* ws = (char*)d_ws;
  unsigned short* xnf = (unsigned short*)(ws + WS_XN);
  unsigned short* wf  = (unsigned short*)(ws + WS_WFRAG);
  unsigned short* wef = (unsigned short*)(ws + WS_WEFRAG);
  float* part   = (float*)(ws + WS_PART);   // stats partials, then sexp[512]
  float* ab     = (float*)(ws + WS_AB);
  float* ctx    = (float*)(ws + WS_CTX);
  float* w2     = (float*)(ws + WS_W2);
  float* weff   = (float*)(ws + WS_WEFF);
  float* beff   = (float*)(ws + WS_BEFF);
  float* out    = (float*)d_out;
  // d_out scratch (consumed by k_ctxred before k_final writes out):
  float* ctxp = (float*)((char*)d_out + 33554432ULL);       //  4 MB
  float* sump = (float*)((char*)d_out + 37748736ULL);       // 64 KB

  k_wfrag<<<512, 64, 0, stream>>>(qkv_w, wf);
  k_stats<<<256, 256, 0, stream>>>(x, part);
  k_coef<<<1, 256, 0, stream>>>(part, gn_w, gn_b, ab);
  k_xn<<<dim3(1024, 4), 256, 0, stream>>>(x, ab, xnf);
  k_kvctx<<<256, 512, 0, stream>>>(xnf, wf, qkv_b, sump, ctxp);
  k_ctxred<<<68, 128, 0, stream>>>(ctxp, sump, ctx, part);
  k_w2<<<512, 256, 0, stream>>>(out_w, ctx, part, w2);
  k_weff<<<256, 256, 0, stream>>>(w2, qkv_w, qkv_b, out_b, weff, beff);
  k_wefrag<<<128, 64, 0, stream>>>(weff, wef);
  k_final<<<512, 256, 0, stream>>>(xnf, wef, beff, out);
}

// Round 18
// 172.129 us; speedup vs baseline: 1.3772x; 1.0001x over previous
//
#include <hip/hip_runtime.h>
#include <stdint.h>

typedef __attribute__((ext_vector_type(8))) short bf16x8;
typedef __attribute__((ext_vector_type(4))) float f32x4;
typedef __attribute__((ext_vector_type(4))) unsigned int u32x4;

#define NSP 65536

// workspace byte offsets
#define WS_XN     0ULL         // 33554432  bf16 xnf fragment-native (kvctx + final)
#define WS_WFRAG  33554432ULL  // 524288    Wkv fragment buffer
#define WS_WEFRAG 34078720ULL  // 131072    Weff fragment buffer
#define WS_PART   34209792ULL  // 2048      stats partials -> reduced sumexp[512]
#define WS_AB     34211840ULL  // 2048      per-channel a,b
#define WS_CTX    34215936ULL  // 131072    ctx[8][64][64]
#define WS_W2     34347008ULL  // 1048576   W2[256][512]
#define WS_WEFF   35395584ULL  // 262144    Weff[256][256]
#define WS_BEFF   35657728ULL  // 1024      beff[256]

// d_out scratch (consumed by k_ctxred before k_final overwrites d_out):
//   ctxp (f32)  [32MB .. 36MB)    256 blocks * 4096 partials
//   sump (f32)  [36MB .. +64KB)   [h*64+d][chunk32]

__device__ __forceinline__ unsigned short f2bf(float f) {
  union { float f; uint32_t u; } v; v.f = f;
  uint32_t r = v.u + 0x7FFFu + ((v.u >> 16) & 1u);
  return (unsigned short)(r >> 16);
}
__device__ __forceinline__ float bf2f(unsigned short b) {
  union { uint32_t u; float f; } v; v.u = ((uint32_t)b) << 16;
  return v.f;
}

// ---------------- GroupNorm stats ----------------
__global__ void k_stats(const float* __restrict__ x, float* __restrict__ part) {
  __shared__ float ss[256], sq[256];
  const int t = threadIdx.x, b = blockIdx.x;
  const f32x4* p = (const f32x4*)(x + (size_t)b * 65536);
  float s = 0.f, qq = 0.f;
  for (int k = 0; k < 64; ++k) {
    f32x4 v = __builtin_nontemporal_load(p + t + 256 * k);
    s  += v[0] + v[1] + v[2] + v[3];
    qq += v[0] * v[0] + v[1] * v[1] + v[2] * v[2] + v[3] * v[3];
  }
  ss[t] = s; sq[t] = qq;
  __syncthreads();
  for (int st = 128; st > 0; st >>= 1) {
    if (t < st) { ss[t] += ss[t + st]; sq[t] += sq[t + st]; }
    __syncthreads();
  }
  if (t == 0) { part[2 * b] = ss[0]; part[2 * b + 1] = sq[0]; }
}

// ---------------- per-channel a,b ----------------
__global__ void k_coef(const float* __restrict__ part, const float* __restrict__ gn_w,
                       const float* __restrict__ gn_b, float* __restrict__ ab) {
  const int c = threadIdx.x;
  const int g = c >> 3;
  float s = 0.f, q = 0.f;
  for (int j = 0; j < 8; ++j) { s += part[(g * 8 + j) * 2]; q += part[(g * 8 + j) * 2 + 1]; }
  const float inv = 1.0f / 524288.0f;
  const float mean = s * inv;
  const float var = q * inv - mean * mean;
  const float rstd = rsqrtf(var + 1e-5f);
  const float a = gn_w[c] * rstd;
  ab[c] = a;
  ab[256 + c] = gn_b[c] - mean * a;
}

// ---------------- normalize + cast -> fragment-native xnf only ----------------
__global__ void k_xn(const float* __restrict__ x, const float* __restrict__ ab,
                     unsigned short* __restrict__ xnf) {
  __shared__ float tile[64][66];
  const int t = threadIdx.x;
  const int nb = blockIdx.x, cb = blockIdx.y;
  {
    const int cl = t >> 2, nc = t & 3;
    const int c = cb * 64 + cl;
    const float a = ab[c], b = ab[256 + c];
    const f32x4* src = (const f32x4*)(x + (size_t)c * NSP + nb * 64 + nc * 16);
#pragma unroll
    for (int j = 0; j < 4; ++j) {
      f32x4 v = __builtin_nontemporal_load(src + j);
      v = v * a + b;
      *(f32x4*)&tile[cl][nc * 16 + j * 4] = v;
    }
  }
  __syncthreads();
  {
    const int l = t & 63, w0 = t >> 6;
    u32x4* xnf4 = (u32x4*)xnf;
#pragma unroll
    for (int u2 = 0; u2 < 2; ++u2) {
      const int fp = w0 + u2 * 4;          // 0..7
      const int fl = fp >> 1, ksl = fp & 1;
      union { unsigned short s[8]; u32x4 v; } pk2;
#pragma unroll
      for (int e = 0; e < 8; ++e)
        pk2.s[e] = f2bf(tile[ksl * 32 + (l >> 4) * 8 + e][fl * 16 + (l & 15)]);
      xnf4[((size_t)(nb * 4 + fl) * 8 + cb * 2 + ksl) * 64 + l] = pk2.v;
    }
  }
}

// ---------------- pre-permute Wkv rows into MFMA B-fragment order ----------------
__global__ void k_wfrag(const float* __restrict__ qkv_w, unsigned short* __restrict__ wf) {
  const int blk = blockIdx.x;                 // blk = ks*64 + cf
  const int l = threadIdx.x;
  const int row = 512 + (blk & 63) * 16 + (l & 15);
  const int c0 = (blk >> 6) * 32 + (l >> 4) * 8;
  const float* src = qkv_w + (size_t)row * 256 + c0;
  union { unsigned short s[8]; u32x4 v; } u;
#pragma unroll
  for (int j = 0; j < 8; ++j) u.s[j] = f2bf(src[j]);
  *(u32x4*)(wf + ((size_t)blk * 64 + l) * 8) = u.v;
}

// ---------------- fused KV-GEMM + exp + in-register context (round-12, 63us) ----------------
__launch_bounds__(512, 1)
__global__ void k_kvctx(const unsigned short* __restrict__ xnf,
                        const unsigned short* __restrict__ wfrag,
                        const float* __restrict__ qkv_b,
                        float* __restrict__ sump, float* __restrict__ ctxp) {
  __shared__ __align__(16) char lds[133120];
  const int t = threadIdx.x;
  const int w = t >> 6, l = t & 63;
  const int q = l & 15;
  const int h = blockIdx.x >> 5;               // head 0..7
  const int chunk = blockIdx.x & 31;           // 2048-row chunk

  // stage this head's wfrag slice (64 KB) once: [ph][ks][jj][l]
  {
    const u32x4* wsrc = (const u32x4*)wfrag;
    u32x4* wdst = (u32x4*)lds;
#pragma unroll
    for (int r = 0; r < 8; ++r) {
      const int e = r * 512 + t;
      const int entry = e >> 6, l2 = e & 63;
      const int ph = entry >> 5, ks = (entry >> 2) & 7, jj = entry & 3;
      wdst[e] = wsrc[((size_t)(ks * 64 + ph * 32 + h * 4 + jj)) * 64 + l2];
    }
  }

  const f32x4 fz = {0.f, 0.f, 0.f, 0.f};
  f32x4 ctxa[4][4];
#pragma unroll
  for (int a = 0; a < 4; ++a)
#pragma unroll
    for (int b = 0; b < 4; ++b) ctxa[a][b] = fz;
  float srow[4] = {0.f, 0.f, 0.f, 0.f};
  float bk[4], bv[4];
#pragma unroll
  for (int jj = 0; jj < 4; ++jj) {
    bk[jj] = qkv_b[512 + h * 64 + jj * 16 + q];
    bv[jj] = qkv_b[1024 + h * 64 + jj * 16 + q];
  }

  const u32x4* xnf4 = (const u32x4*)xnf;
  u32x4* xa4 = (u32x4*)(lds + 65536);

  for (int st = 0; st < 8; ++st) {
    const size_t rg0 = (size_t)chunk * 128 + st * 16;  // first row-group of super-tile
    __syncthreads();               // previous tile's reads done
#pragma unroll
    for (int r = 0; r < 8; ++r)
      xa4[r * 512 + t] = xnf4[rg0 * 512 + r * 512 + t];
    __syncthreads();
    const u32x4* gB = xnf4 + (rg0 + 8 + w) * 512 + l;

    // K phase: both groups share the bwk LDS reads
    f32x4 ak[2][4] = {{fz, fz, fz, fz}, {fz, fz, fz, fz}};
#pragma unroll
    for (int ks = 0; ks < 8; ++ks) {
      const bf16x8 xaA = *(const bf16x8*)(lds + 65536 + ((w * 8 + ks) * 64 + l) * 16);
      const bf16x8 xaB = *(const bf16x8*)(gB + ks * 64);
#pragma unroll
      for (int jj = 0; jj < 4; ++jj) {
        const bf16x8 bwk = *(const bf16x8*)(lds + ((ks * 4 + jj) * 64 + l) * 16);
        ak[0][jj] = __builtin_amdgcn_mfma_f32_16x16x32_bf16(xaA, bwk, ak[0][jj], 0, 0, 0);
        ak[1][jj] = __builtin_amdgcn_mfma_f32_16x16x32_bf16(xaB, bwk, ak[1][jj], 0, 0, 0);
      }
    }
    bf16x8 pk[4];
#pragma unroll
    for (int jj = 0; jj < 4; ++jj) {
      float s = 0.f;
      bf16x8 p;
#pragma unroll
      for (int r = 0; r < 4; ++r) {
        const unsigned short u0 = f2bf(__expf(ak[0][jj][r] + bk[jj]));
        const unsigned short u1 = f2bf(__expf(ak[1][jj][r] + bk[jj]));
        p[r] = (short)u0; p[r + 4] = (short)u1;
        s += bf2f(u0) + bf2f(u1);
      }
      pk[jj] = p;
      srow[jj] += s;
    }

    // V phase
    f32x4 av[2][4] = {{fz, fz, fz, fz}, {fz, fz, fz, fz}};
#pragma unroll
    for (int ks = 0; ks < 8; ++ks) {
      const bf16x8 xaA = *(const bf16x8*)(lds + 65536 + ((w * 8 + ks) * 64 + l) * 16);
      const bf16x8 xaB = *(const bf16x8*)(gB + ks * 64);
#pragma unroll
      for (int jj = 0; jj < 4; ++jj) {
        const bf16x8 bwv = *(const bf16x8*)(lds + (((8 + ks) * 4 + jj) * 64 + l) * 16);
        av[0][jj] = __builtin_amdgcn_mfma_f32_16x16x32_bf16(xaA, bwv, av[0][jj], 0, 0, 0);
        av[1][jj] = __builtin_amdgcn_mfma_f32_16x16x32_bf16(xaB, bwv, av[1][jj], 0, 0, 0);
      }
    }
    bf16x8 pv[4];
#pragma unroll
    for (int jj = 0; jj < 4; ++jj) {
      bf16x8 p;
#pragma unroll
      for (int r = 0; r < 4; ++r) {
        p[r]     = (short)f2bf(av[0][jj][r] + bv[jj]);
        p[r + 4] = (short)f2bf(av[1][jj][r] + bv[jj]);
      }
      pv[jj] = p;
    }

    // context accumulate: full K=32 (both groups)
#pragma unroll
    for (int ja = 0; ja < 4; ++ja)
#pragma unroll
      for (int jb = 0; jb < 4; ++jb)
        ctxa[ja][jb] = __builtin_amdgcn_mfma_f32_16x16x32_bf16(pk[ja], pv[jb], ctxa[ja][jb], 0, 0, 0);
  }

  // ---- block-level reduction (8 waves, same head) ----
  __syncthreads();
  {
    float* dw = (float*)lds + w * 4096 + l * 4;
#pragma unroll
    for (int ja = 0; ja < 4; ++ja)
#pragma unroll
      for (int jb = 0; jb < 4; ++jb)
        *(f32x4*)(dw + (ja * 4 + jb) * 256) = ctxa[ja][jb];
  }
  {
    float* srl = (float*)(lds + 131072);
#pragma unroll
    for (int jj = 0; jj < 4; ++jj) {
      float s = srow[jj];
      s += __shfl_xor(s, 16, 64);
      s += __shfl_xor(s, 32, 64);
      if (l < 16) srl[w * 64 + jj * 16 + q] = s;
    }
  }
  __syncthreads();
  {
    const float* dump = (const float*)lds;
    const f32x4 fz2 = {0.f, 0.f, 0.f, 0.f};
#pragma unroll
    for (int j = 0; j < 2; ++j) {
      const int m4 = j * 512 + t;            // 0..1024 f32x4 outputs
      f32x4 s = fz2;
#pragma unroll
      for (int w8 = 0; w8 < 8; ++w8)
        s += *(const f32x4*)(dump + w8 * 4096 + m4 * 4);
      *(f32x4*)(ctxp + ((size_t)(h * 32 + chunk) * 1024 + m4) * 4) = s;
    }
    if (t < 64) {
      const float* srl = (const float*)(lds + 131072);
      float s = 0.f;
#pragma unroll
      for (int w8 = 0; w8 < 8; ++w8) s += srl[w8 * 64 + t];
      sump[(size_t)(h * 64 + t) * 32 + chunk] = s;
    }
  }
}

// ---------------- reduce partials over 32 chunks ----------------
__global__ void k_ctxred(const float* __restrict__ ctxp, const float* __restrict__ sump,
                         float* __restrict__ ctx, float* __restrict__ sexp) {
  const int t = threadIdx.x;
  if (blockIdx.x < 64) {
    const int m4 = blockIdx.x * 128 + t;     // 0..8192
    const int h = m4 >> 10, p4 = m4 & 1023;
    f32x4 s = {0.f, 0.f, 0.f, 0.f};
#pragma unroll 8
    for (int c = 0; c < 32; ++c)
      s += *(const f32x4*)(ctxp + (((size_t)h * 32 + c) * 1024 + p4) * 4);
    const int jajb = p4 >> 6, ll = p4 & 63;
    const int ja = jajb >> 2, jb = jajb & 3;
    const int gg = ll >> 4, qq = ll & 15;
    float* cw = ctx + ((size_t)h * 64 + ja * 16 + gg * 4) * 64 + jb * 16 + qq;
    cw[0] = s[0]; cw[64] = s[1]; cw[128] = s[2]; cw[192] = s[3];
  } else {
    const int r = (blockIdx.x - 64) * 128 + t;
    float s = 0.f;
#pragma unroll 8
    for (int c = 0; c < 32; ++c) s += sump[(size_t)r * 32 + c];
    sexp[r] = s;
  }
}

// ---------------- W2 ----------------
__global__ void k_w2(const float* __restrict__ out_w, const float* __restrict__ ctx,
                     const float* __restrict__ sexp, float* __restrict__ w2) {
  const int r = blockIdx.x;
  const int h = r >> 6, d = r & 63;
  __shared__ float row[64];
  __shared__ float sinv;
  const int t = threadIdx.x;
  if (t < 64) row[t] = ctx[((size_t)h * 64 + d) * 64 + t];
  if (t == 0) sinv = 1.0f / sexp[r];
  __syncthreads();
  float a = 0.f;
  const float* wp = out_w + (size_t)t * 512 + h * 64;
#pragma unroll 8
  for (int e = 0; e < 64; ++e) a += wp[e] * row[e];
  w2[(size_t)t * 512 + r] = a * sinv;
}

// ---------------- Weff = W2 @ Wq  (+ beff folded in) ----------------
__global__ void k_weff(const float* __restrict__ w2, const float* __restrict__ qkv_w,
                       const float* __restrict__ qkv_b, const float* __restrict__ out_b,
                       float* __restrict__ weff, float* __restrict__ beff) {
  const int o = blockIdx.x;
  const int c = threadIdx.x;
  __shared__ float row[512];
  __shared__ float red[256];
  row[c] = w2[(size_t)o * 512 + c];
  row[256 + c] = w2[(size_t)o * 512 + 256 + c];
  __syncthreads();
  float a = 0.f;
#pragma unroll 8
  for (int r = 0; r < 512; ++r) a += row[r] * qkv_w[(size_t)r * 256 + c];
  weff[o * 256 + c] = a;
  red[c] = row[c] * qkv_b[c] + row[256 + c] * qkv_b[256 + c];
  __syncthreads();
  for (int st = 128; st > 0; st >>= 1) {
    if (c < st) red[c] += red[c + st];
    __syncthreads();
  }
  if (c == 0) beff[o] = out_b[o] + red[0];
}

// ---------------- Weff -> fragment order ----------------
__global__ void k_wefrag(const float* __restrict__ weff, unsigned short* __restrict__ wf) {
  const int blk = blockIdx.x;
  const int l = threadIdx.x;
  const int row = (blk & 15) * 16 + (l & 15);
  const int c0 = (blk >> 4) * 32 + (l >> 4) * 8;
  const float* src = weff + (size_t)row * 256 + c0;
  union { unsigned short s[8]; u32x4 v; } u;
#pragma unroll
  for (int j = 0; j < 8; ++j) u.s[j] = f2bf(src[j]);
  *(u32x4*)(wf + ((size_t)blk * 64 + l) * 8) = u.v;
}

// ---------------- final GEMM (reads xnf fragments) + coalesced epilogue ----------------
__launch_bounds__(256, 2)
__global__ void k_final(const unsigned short* __restrict__ xnf,
                        const unsigned short* __restrict__ wef,
                        const float* __restrict__ beff,
                        float* __restrict__ out) {
  __shared__ unsigned short xlds[32768];   // 64 KB fragment staging, reused for transpose
  const int t = threadIdx.x;
  const int w = t >> 6, l = t & 63;
  const int q = l & 15, g = l >> 4;
  const int si = w >> 1, sj = w & 1;
  // XCD swizzle: each XCD (bid%8) owns a contiguous 8192-column span of every row
  const int bid = (blockIdx.x & 7) * 64 + (blockIdx.x >> 3);
  const size_t n0 = (size_t)bid * 128;
  {
    const u32x4* gs = (const u32x4*)xnf + (size_t)bid * 4096;
    u32x4* ld = (u32x4*)xlds;
#pragma unroll
    for (int k2 = 0; k2 < 16; ++k2)
      ld[t + 256 * k2] = gs[t + 256 * k2];
  }
  __syncthreads();
  const f32x4 fz = {0.f, 0.f, 0.f, 0.f};
  f32x4 acc[4][8];
#pragma unroll
  for (int i = 0; i < 4; ++i)
#pragma unroll
    for (int j = 0; j < 8; ++j) acc[i][j] = fz;
#pragma unroll
  for (int ks = 0; ks < 8; ++ks) {
    bf16x8 xa[4];
#pragma unroll
    for (int i = 0; i < 4; ++i)
      xa[i] = *(const bf16x8*)((const char*)xlds + (((si * 4 + i) * 8 + ks) * 64 + l) * 16);
#pragma unroll
    for (int jj = 0; jj < 8; ++jj) {
      const bf16x8 bw = *(const bf16x8*)(wef + (((size_t)(ks * 16 + sj * 8 + jj)) * 64 + l) * 8);
#pragma unroll
      for (int i = 0; i < 4; ++i)
        acc[i][jj] = __builtin_amdgcn_mfma_f32_16x16x32_bf16(xa[i], bw, acc[i][jj], 0, 0, 0);
    }
  }
  // transpose epilogue through LDS: 4 rounds of 64 output rows
  __syncthreads();
  float* trf = (float*)xlds;               // [64][129] floats
#pragma unroll
  for (int k4 = 0; k4 < 4; ++k4) {
    if ((k4 >> 1) == sj) {
#pragma unroll
      for (int jj2 = 0; jj2 < 4; ++jj2) {
        const int jj = (k4 & 1) * 4 + jj2;
        const float be = beff[sj * 128 + jj * 16 + q];
#pragma unroll
        for (int i = 0; i < 4; ++i)
#pragma unroll
          for (int r = 0; r < 4; ++r)
            trf[(jj2 * 16 + q) * 129 + si * 64 + i * 16 + g * 4 + r] = acc[i][jj][r] + be;
      }
    }
    __syncthreads();
#pragma unroll
    for (int j = 0; j < 32; ++j) {
      const int mm = j * 256 + t;          // 8192 floats
      const int ol = mm >> 7, cc = mm & 127;
      out[(size_t)(k4 * 64 + ol) * NSP + n0 + cc] = trf[ol * 129 + cc];
    }
    __syncthreads();
  }
}

extern "C" void kernel_launch(void* const* d_in, const int* in_sizes, int n_in,
                              void* d_out, int out_size, void* d_ws, size_t ws_size,
                              hipStream_t stream) {
  const float* x     = (const float*)d_in[0];
  const float* gn_w  = (const float*)d_in[1];
  const float* gn_b  = (const float*)d_in[2];
  const float* qkv_w = (const float*)d_in[3];
  const float* qkv_b = (const float*)d_in[4];
  const float* out_w = (const float*)d_in[5];
  const float* out_b = (const float*)d_in[6];
  char* ws = (char*)d_ws;
  unsigned short* xnf = (unsigned short*)(ws + WS_XN);
  unsigned short* wf  = (unsigned short*)(ws + WS_WFRAG);
  unsigned short* wef = (unsigned short*)(ws + WS_WEFRAG);
  float* part   = (float*)(ws + WS_PART);   // stats partials, then sexp[512]
  float* ab     = (float*)(ws + WS_AB);
  float* ctx    = (float*)(ws + WS_CTX);
  float* w2     = (float*)(ws + WS_W2);
  float* weff   = (float*)(ws + WS_WEFF);
  float* beff   = (float*)(ws + WS_BEFF);
  float* out    = (float*)d_out;
  // d_out scratch (consumed by k_ctxred before k_final writes out):
  float* ctxp = (float*)((char*)d_out + 33554432ULL);       //  4 MB
  float* sump = (float*)((char*)d_out + 37748736ULL);       // 64 KB

  k_wfrag<<<512, 64, 0, stream>>>(qkv_w, wf);
  k_stats<<<256, 256, 0, stream>>>(x, part);
  k_coef<<<1, 256, 0, stream>>>(part, gn_w, gn_b, ab);
  k_xn<<<dim3(1024, 4), 256, 0, stream>>>(x, ab, xnf);
  k_kvctx<<<256, 512, 0, stream>>>(xnf, wf, qkv_b, sump, ctxp);
  k_ctxred<<<68, 128, 0, stream>>>(ctxp, sump, ctx, part);
  k_w2<<<512, 256, 0, stream>>>(out_w, ctx, part, w2);
  k_weff<<<256, 256, 0, stream>>>(w2, qkv_w, qkv_b, out_b, weff, beff);
  k_wefrag<<<128, 64, 0, stream>>>(weff, wef);
  k_final<<<512, 256, 0, stream>>>(xnf, wef, beff, out);
}